// Round 10
// baseline (112.512 us; speedup 1.0000x reference)
//
#include <hip/hip_runtime.h>
#include <math.h>

// MidpointMLR: B=1048576, F=64, c=1.
// out = proj( sinh( 2*z_norm * asinh( (2*(x@zu)*cosh(2b) - (1+cx2)*sinh(2b)) / max(1-cx2,eps) ) ) )

#define MLR_B 1048576

typedef __bf16 bf16x8 __attribute__((ext_vector_type(8)));
typedef float  f32x4  __attribute__((ext_vector_type(4)));

// ---------------- prep: z -> z_unit bf16 fragments + per-col constants ----------------
// k-permutation shared by A and B fragments: k = 16*i + 4*hi + j,
//   where i = 2s + (e>>2)  (load-instruction index), j = e&3, hi = lane>>4.
// Column permutation: B-fragment t, mfma-col c  <->  physical col p = 4c + t
//   (so each lane's 4 accumulators are 4 CONSECUTIVE physical cols -> dwordx4 stores).
// ws layout: bytes [0,8192): zfrag[8][512] __bf16, frag (s*4+t):
//   zf[(s*4+t)*512 + (hi*16+c)*8 + e] = bf16( z_unit[k(s,e,hi)][4c+t] )
// bytes [8192,9216): f32x4 cst4[64] = {2cosh(2b), sinh(2b), 2*z_norm, 0} per physical col
// Parallel version: 256 threads = (kq = tid>>6 in 0..3) x (o = tid&63), LDS-reduced norms.
__global__ __launch_bounds__(256) void mlr_prep_kernel(const float* __restrict__ z,
                                                       const float* __restrict__ bias,
                                                       void* __restrict__ wsv) {
    __bf16* zf   = (__bf16*)wsv;
    f32x4*  cst4 = (f32x4*)((char*)wsv + 8192);
    __shared__ float part[4][64];
    __shared__ float invs[64];

    const int tid = threadIdx.x;
    const int o   = tid & 63;       // physical output column
    const int kq  = tid >> 6;       // k-quarter: 16 k's each

    float n2 = 0.f;
#pragma unroll
    for (int kk = 0; kk < 16; ++kk) {
        int k = kq * 16 + kk;
        float v = z[k * 64 + o];
        n2 = fmaf(v, v, n2);
    }
    part[kq][o] = n2;
    __syncthreads();

    if (tid < 64) {
        float tot = part[0][o] + part[1][o] + part[2][o] + part[3][o];
        float zn  = fmaxf(sqrtf(tot), 1e-15f);
        invs[o] = 1.f / zn;
        float d = 2.f * bias[o];
        cst4[o] = (f32x4){2.f * coshf(d), sinhf(d), 2.f * zn, 0.f};
    }
    __syncthreads();

    const float inv = invs[o];
    const int t = o & 3, c = o >> 2;    // fragment index, mfma-col slot
#pragma unroll
    for (int kk = 0; kk < 16; ++kk) {
        int k  = kq * 16 + kk;
        float zu = z[k * 64 + o] * inv;
        int i  = k >> 4;            // which 64B column-chunk (load instr)
        int j  = k & 3;
        int hi = (k >> 2) & 3;
        int s  = i >> 1;
        int e  = ((i & 1) << 2) | j;
        zf[(s * 4 + t) * 512 + (hi * 16 + c) * 8 + e] = (__bf16)zu;   // RNE fptrunc
    }
}

// y = sinh( g * asinh(t) ) via exp2/log2, stable in |t|
// NB: __builtin_amdgcn_logf IS v_log_f32 = log2 (see __clang_hip_math.h __log2f)
__device__ __forceinline__ float poin_y(float dot, float ch2, float sh, float g,
                                        float opc, float rden) {
    float t = fmaf(dot, ch2, -(opc * sh)) * rden;
    float a = fabsf(t);
    float u = a + sqrtf(fmaf(a, a, 1.f));
    float w = __builtin_amdgcn_exp2f(g * __builtin_amdgcn_logf(u));   // u^g
    float y = 0.5f * (w - __builtin_amdgcn_rcpf(w));
    return copysignf(y, t);
}

// one 16-row MFMA step: c0..c3 = this lane's x slice (row lo, k = 16i+4hi+j)
__device__ __forceinline__ void mlr_step(f32x4 c0, f32x4 c1, f32x4 c2, f32x4 c3,
                                         const bf16x8* bfr, const f32x4* cc,
                                         int lo, int hi, char* ob) {
    // cx2 for row lo (sum across hi groups)
    float p = 0.f;
#pragma unroll
    for (int j = 0; j < 4; ++j) {
        p = fmaf(c0[j], c0[j], p); p = fmaf(c1[j], c1[j], p);
        p = fmaf(c2[j], c2[j], p); p = fmaf(c3[j], c3[j], p);
    }
    p += __shfl_xor(p, 16);
    p += __shfl_xor(p, 32);

    // A fragments (same k-perm as B)
    bf16x8 a0, a1;
#pragma unroll
    for (int j = 0; j < 4; ++j) {
        a0[j]     = (__bf16)c0[j];
        a0[4 + j] = (__bf16)c1[j];
        a1[j]     = (__bf16)c2[j];
        a1[4 + j] = (__bf16)c3[j];
    }

    f32x4 acc[4];
#pragma unroll
    for (int t = 0; t < 4; ++t) {
        acc[t] = (f32x4){0.f, 0.f, 0.f, 0.f};
        acc[t] = __builtin_amdgcn_mfma_f32_16x16x32_bf16(a0, bfr[t],     acc[t], 0, 0, 0);
        acc[t] = __builtin_amdgcn_mfma_f32_16x16x32_bf16(a1, bfr[4 + t], acc[t], 0, 0, 0);
    }

    // epilogue: C/D map col=lo, row=4*hi+reg; acc[t][r] = physical col 4*lo+t
    f32x4 yv[4]; float S[4];
#pragma unroll
    for (int r = 0; r < 4; ++r) {
        float cxr  = __shfl(p, hi * 4 + r);            // cx2 of row 4*hi+r
        float opc  = 1.f + cxr;
        float rden = __builtin_amdgcn_rcpf(fmaxf(1.f - cxr, 1e-15f));
        float s0 = 0.f;
        f32x4 y;
#pragma unroll
        for (int t = 0; t < 4; ++t) {
            float v = poin_y(acc[t][r], cc[t].x, cc[t].y, cc[t].z, opc, rden);
            y[t] = v;
            s0 = fmaf(v, v, s0);
        }
        yv[r] = y;
        S[r] = s0;
    }
#pragma unroll
    for (int r = 0; r < 4; ++r) {
        float s0 = S[r];
        s0 += __shfl_xor(s0, 1);
        s0 += __shfl_xor(s0, 2);
        s0 += __shfl_xor(s0, 4);
        s0 += __shfl_xor(s0, 8);                       // sum over all 64 cols of row
        float scale = __builtin_amdgcn_rcpf(1.f + sqrtf(1.f + s0));
        f32x4 y = yv[r];
        y[0] *= scale; y[1] *= scale; y[2] *= scale; y[3] *= scale;
        yv[r] = y;
    }

    // stores: one NONTEMPORAL dwordx4 per r (no L2 allocate; write-once stream)
    // 64 lanes cover rows {4hi+r} x cols 4lo..4lo+3 = 4 x 256B contiguous rows/instr
#pragma unroll
    for (int r = 0; r < 4; ++r)
        __builtin_nontemporal_store(yv[r], (f32x4*)(ob + r * 256));
}

// ---------------- main: 2 steps per wave, straight-line, all loads upfront ----------------
__global__ __launch_bounds__(256) void mlr_main_kernel(const float* __restrict__ x,
                                                       const void* __restrict__ wsv,
                                                       float* __restrict__ out) {
    const __bf16* zf   = (const __bf16*)wsv;
    const f32x4*  cst4 = (const f32x4*)((const char*)wsv + 8192);
    const int tid  = threadIdx.x;
    const int lane = tid & 63;
    const int lo   = lane & 15;     // A-row / B-col / C-col index
    const int hi   = lane >> 4;     // k-group / C-row-group
    const int wv   = blockIdx.x * 4 + (tid >> 6);

    // B fragments (z_unit): 8 coalesced dwordx4 (L2-resident, keep cached)
    bf16x8 bfr[8];
#pragma unroll
    for (int i = 0; i < 8; ++i)
        bfr[i] = *(const bf16x8*)((const char*)zf + i * 1024 + lane * 16);
    // per-col epilogue constants for physical cols 4lo+t (64B contiguous per lane)
    f32x4 cc[4];
#pragma unroll
    for (int t = 0; t < 4; ++t) cc[t] = cst4[4 * lo + t];

    const size_t rowbase = (size_t)wv * 32;            // 2 steps x 16 rows
    // load i hits bytes [i*64 + hi*16, +16) of row lo: 16 full 64B lines/instr
    const char* xb = (const char*)x + (rowbase + (size_t)lo) * 256 + hi * 16;

    // issue ALL x loads for both steps upfront — nontemporal (read-once stream)
    f32x4 c0 = __builtin_nontemporal_load((const f32x4*)(xb + 0));
    f32x4 c1 = __builtin_nontemporal_load((const f32x4*)(xb + 64));
    f32x4 c2 = __builtin_nontemporal_load((const f32x4*)(xb + 128));
    f32x4 c3 = __builtin_nontemporal_load((const f32x4*)(xb + 192));
    f32x4 d0 = __builtin_nontemporal_load((const f32x4*)(xb + 4096 + 0));
    f32x4 d1 = __builtin_nontemporal_load((const f32x4*)(xb + 4096 + 64));
    f32x4 d2 = __builtin_nontemporal_load((const f32x4*)(xb + 4096 + 128));
    f32x4 d3 = __builtin_nontemporal_load((const f32x4*)(xb + 4096 + 192));

    char* ob = (char*)out + (rowbase + (size_t)hi * 4) * 256 + lo * 16;
    mlr_step(c0, c1, c2, c3, bfr, cc, lo, hi, ob);
    mlr_step(d0, d1, d2, d3, bfr, cc, lo, hi, ob + 4096);
}

extern "C" void kernel_launch(void* const* d_in, const int* in_sizes, int n_in,
                              void* d_out, int out_size, void* d_ws, size_t ws_size,
                              hipStream_t stream) {
    const float* x    = (const float*)d_in[0];
    const float* z    = (const float*)d_in[1];
    const float* bias = (const float*)d_in[2];
    float* out = (float*)d_out;

    mlr_prep_kernel<<<dim3(1), dim3(256), 0, stream>>>(z, bias, d_ws);
    mlr_main_kernel<<<dim3(8192), dim3(256), 0, stream>>>(x, d_ws, out);
}

// Round 11
// 96.617 us; speedup vs baseline: 1.1645x; 1.1645x over previous
//
#include <hip/hip_runtime.h>
#include <math.h>

// MidpointMLR: B=1048576, F=64, c=1.
// out = proj( sinh( 2*z_norm * asinh( (2*(x@zu)*cosh(2b) - (1+cx2)*sinh(2b)) / max(1-cx2,eps) ) ) )

#define MLR_B 1048576

typedef __bf16 bf16x8 __attribute__((ext_vector_type(8)));
typedef float  f32x4  __attribute__((ext_vector_type(4)));

// ---------------- prep: z -> z_unit bf16 fragments + per-col constants ----------------
// k-permutation shared by A and B fragments: k = 16*i + 4*hi + j.
// Column permutation: B-fragment t, mfma-col c <-> physical col p = 4c + t.
// ws layout: bytes [0,8192): zfrag[8][512] __bf16, frag (s*4+t):
//   zf[(s*4+t)*512 + (hi*16+c)*8 + e] = bf16( z_unit[k(s,e,hi)][4c+t] )
// bytes [8192,9216): f32x4 cst4[64] = {2cosh(2b), sinh(2b), 2*z_norm, 0} per physical col
__global__ __launch_bounds__(256) void mlr_prep_kernel(const float* __restrict__ z,
                                                       const float* __restrict__ bias,
                                                       void* __restrict__ wsv) {
    __bf16* zf   = (__bf16*)wsv;
    f32x4*  cst4 = (f32x4*)((char*)wsv + 8192);
    __shared__ float part[4][64];
    __shared__ float invs[64];

    const int tid = threadIdx.x;
    const int o   = tid & 63;       // physical output column
    const int kq  = tid >> 6;       // k-quarter: 16 k's each

    float n2 = 0.f;
#pragma unroll
    for (int kk = 0; kk < 16; ++kk) {
        int k = kq * 16 + kk;
        float v = z[k * 64 + o];
        n2 = fmaf(v, v, n2);
    }
    part[kq][o] = n2;
    __syncthreads();

    if (tid < 64) {
        float tot = part[0][o] + part[1][o] + part[2][o] + part[3][o];
        float zn  = fmaxf(sqrtf(tot), 1e-15f);
        invs[o] = 1.f / zn;
        float d = 2.f * bias[o];
        cst4[o] = (f32x4){2.f * coshf(d), sinhf(d), 2.f * zn, 0.f};
    }
    __syncthreads();

    const float inv = invs[o];
    const int t = o & 3, c = o >> 2;    // fragment index, mfma-col slot
#pragma unroll
    for (int kk = 0; kk < 16; ++kk) {
        int k  = kq * 16 + kk;
        float zu = z[k * 64 + o] * inv;
        int i  = k >> 4;
        int j  = k & 3;
        int hi = (k >> 2) & 3;
        int s  = i >> 1;
        int e  = ((i & 1) << 2) | j;
        zf[(s * 4 + t) * 512 + (hi * 16 + c) * 8 + e] = (__bf16)zu;   // RNE fptrunc
    }
}

// y = sinh( g * asinh(t) ) via exp2/log2 — sign-transparent: u = t+sqrt(1+t^2) > 0
// for all t, and (u^g - u^-g)/2 has the right sign automatically (|t| <~ 3 here,
// no cancellation at required accuracy).
// NB: __builtin_amdgcn_logf IS v_log_f32 = log2.
__device__ __forceinline__ float poin_y(float dot, float ch2, float sh, float g,
                                        float opc, float rden) {
    float t = fmaf(dot, ch2, -(opc * sh)) * rden;
    float u = t + sqrtf(fmaf(t, t, 1.f));
    float w = __builtin_amdgcn_exp2f(g * __builtin_amdgcn_logf(u));   // u^g
    return 0.5f * (w - __builtin_amdgcn_rcpf(w));
}

struct StepMid {
    f32x4 acc[4];
    float p;        // cx2 for row lo
};

// gemm phase: cx2 + bf16 pack + 8 MFMA. c0..c3 die here.
__device__ __forceinline__ StepMid mlr_gemm(f32x4 c0, f32x4 c1, f32x4 c2, f32x4 c3,
                                            const bf16x8* bfr) {
    StepMid m;
    float p = 0.f;
#pragma unroll
    for (int j = 0; j < 4; ++j) {
        p = fmaf(c0[j], c0[j], p); p = fmaf(c1[j], c1[j], p);
        p = fmaf(c2[j], c2[j], p); p = fmaf(c3[j], c3[j], p);
    }
    p += __shfl_xor(p, 16);
    p += __shfl_xor(p, 32);
    m.p = p;

    bf16x8 a0, a1;
#pragma unroll
    for (int j = 0; j < 4; ++j) {
        a0[j]     = (__bf16)c0[j];
        a0[4 + j] = (__bf16)c1[j];
        a1[j]     = (__bf16)c2[j];
        a1[4 + j] = (__bf16)c3[j];
    }

#pragma unroll
    for (int t = 0; t < 4; ++t) {
        m.acc[t] = (f32x4){0.f, 0.f, 0.f, 0.f};
        m.acc[t] = __builtin_amdgcn_mfma_f32_16x16x32_bf16(a0, bfr[t],     m.acc[t], 0, 0, 0);
        m.acc[t] = __builtin_amdgcn_mfma_f32_16x16x32_bf16(a1, bfr[4 + t], m.acc[t], 0, 0, 0);
    }
    return m;
}

// finish phase: transcendental epilogue + projection + nt stores.
// C/D map col=lo, row=4*hi+reg; acc[t][r] = physical col 4*lo+t.
__device__ __forceinline__ void mlr_fin(const StepMid& m, const f32x4* cc,
                                        int lo, int hi, char* ob) {
    f32x4 yv[4]; float S[4];
#pragma unroll
    for (int r = 0; r < 4; ++r) {
        float cxr  = __shfl(m.p, hi * 4 + r);          // cx2 of row 4*hi+r
        float opc  = 1.f + cxr;
        float rden = __builtin_amdgcn_rcpf(fmaxf(1.f - cxr, 1e-15f));
        float s0 = 0.f;
        f32x4 y;
#pragma unroll
        for (int t = 0; t < 4; ++t) {
            float v = poin_y(m.acc[t][r], cc[t].x, cc[t].y, cc[t].z, opc, rden);
            y[t] = v;
            s0 = fmaf(v, v, s0);
        }
        yv[r] = y;
        S[r] = s0;
    }
#pragma unroll
    for (int r = 0; r < 4; ++r) {
        float s0 = S[r];
        s0 += __shfl_xor(s0, 1);
        s0 += __shfl_xor(s0, 2);
        s0 += __shfl_xor(s0, 4);
        s0 += __shfl_xor(s0, 8);                       // sum over all 64 cols of row
        float scale = __builtin_amdgcn_rcpf(1.f + sqrtf(1.f + s0));
        f32x4 y = yv[r];
        y[0] *= scale; y[1] *= scale; y[2] *= scale; y[3] *= scale;
        yv[r] = y;
    }
#pragma unroll
    for (int r = 0; r < 4; ++r)
        __builtin_nontemporal_store(yv[r], (f32x4*)(ob + r * 256));
}

// ---------------- main: 2 steps/wave; step-1 loads issued under step-0 epilogue ----------------
__global__ __launch_bounds__(256, 4) void mlr_main_kernel(const float* __restrict__ x,
                                                          const void* __restrict__ wsv,
                                                          float* __restrict__ out) {
    const __bf16* zf   = (const __bf16*)wsv;
    const f32x4*  cst4 = (const f32x4*)((const char*)wsv + 8192);
    const int tid  = threadIdx.x;
    const int lane = tid & 63;
    const int lo   = lane & 15;     // A-row / B-col / C-col index
    const int hi   = lane >> 4;     // k-group / C-row-group
    const int wv   = blockIdx.x * 4 + (tid >> 6);

    // B fragments (z_unit): 8 coalesced dwordx4 (L2-resident, cached)
    bf16x8 bfr[8];
#pragma unroll
    for (int i = 0; i < 8; ++i)
        bfr[i] = *(const bf16x8*)((const char*)zf + i * 1024 + lane * 16);
    // per-col epilogue constants for physical cols 4lo+t
    f32x4 cc[4];
#pragma unroll
    for (int t = 0; t < 4; ++t) cc[t] = cst4[4 * lo + t];

    const size_t rowbase = (size_t)wv * 32;            // 2 steps x 16 rows
    // load i hits bytes [i*64 + hi*16, +16) of row lo: 16 full 64B lines/instr
    const char* xb = (const char*)x + (rowbase + (size_t)lo) * 256 + hi * 16;
    char* ob = (char*)out + (rowbase + (size_t)hi * 4) * 256 + lo * 16;

    // step 0 loads
    f32x4 c0 = *(const f32x4*)(xb + 0);
    f32x4 c1 = *(const f32x4*)(xb + 64);
    f32x4 c2 = *(const f32x4*)(xb + 128);
    f32x4 c3 = *(const f32x4*)(xb + 192);

    StepMid m0 = mlr_gemm(c0, c1, c2, c3, bfr);

    // step 1 loads: issued now, latency hidden under step-0 epilogue
    f32x4 d0 = *(const f32x4*)(xb + 4096 + 0);
    f32x4 d1 = *(const f32x4*)(xb + 4096 + 64);
    f32x4 d2 = *(const f32x4*)(xb + 4096 + 128);
    f32x4 d3 = *(const f32x4*)(xb + 4096 + 192);

    mlr_fin(m0, cc, lo, hi, ob);

    StepMid m1 = mlr_gemm(d0, d1, d2, d3, bfr);
    mlr_fin(m1, cc, lo, hi, ob + 4096);
}

extern "C" void kernel_launch(void* const* d_in, const int* in_sizes, int n_in,
                              void* d_out, int out_size, void* d_ws, size_t ws_size,
                              hipStream_t stream) {
    const float* x    = (const float*)d_in[0];
    const float* z    = (const float*)d_in[1];
    const float* bias = (const float*)d_in[2];
    float* out = (float*)d_out;

    mlr_prep_kernel<<<dim3(1), dim3(256), 0, stream>>>(z, bias, d_ws);
    mlr_main_kernel<<<dim3(8192), dim3(256), 0, stream>>>(x, d_ws, out);
}